// Round 12
// baseline (812.158 us; speedup 1.0000x reference)
//
#include <hip/hip_runtime.h>
#include <cstdint>
#include <cstddef>

#define BB 8
#define CC 64
#define NN 4096
#define OO 64
#define KK 20
#define KC 58
#define HC 29             // channels per lane (lane-pair split: even 0-28, odd 29-57)
#define KSKIP 6
#define NSPLIT 8
#define JS 512            // j's per split
#define TIDX 8            // tracked depth per split (values AND indices)
#define REC 16            // candvx record: 8 values + 8 indices (words)
#define FBCAP 96
#define BN_EPS 1e-5f
#define NEG 0.2f
#define NEGINF (-3.402823466e38f)
#define M_TOTAL 655360.0f   // B*N*K
// odd-half LDS tile offset: 29*64 words == 0 mod 32 banks -> collides with the
// even half's bank group (r7: SQ_LDS_BANK_CONFLICT 1.2e8 = 37% of cycles).
// Shift odd half by +4 words (r8: conflicts -> 0).
#define HPAD 4

#define MED3F(a, b, c) __builtin_amdgcn_fmed3f((a), (b), (c))

// DEPTH-8 SINGLE-PASS (r12): k_knnA is VALU-issue-bound (r11: VALUBusy 82%,
// occupancy-insensitive). RIPX-20 spent 12 med3/elem maintaining tv[8..19]
// solely for the exact threshold. Now: per-split top-8 (values+indices).
// Threshold = 20th of the 8x8=64 tracked values; EXACT unless some split's
// 8th value >= thr (hidden-qualifier argument: hidden v in S => S.v[7] >= v
// >= thr_true >= thr_cand => detection fires). Detection ~3% queries -> k_fb
// computes its own exact threshold (per-thread RIP + LDS tree merge) and
// selection, bit-exact d chain.
// VGPR-CAP MODEL (r0-r5): cap = 256/min_waves_arg; residency halves at alloc
// {64,128,256}. SPILL TRIPWIRE: k_knnA FETCH_SIZE ~31 MB. GBs = spill.

// ---------------- K0: h = 0.5*||x_{6:}||^2 per point ----------------
__global__ void k_sq(const float* __restrict__ x, float* __restrict__ h) {
  int n = blockIdx.x * 256 + threadIdx.x;  // 0 .. BB*NN-1
  int b = n >> 12;
  int nn = n & (NN - 1);
  const float* xp = x + ((size_t)b * CC + KSKIP) * NN + nn;
  float s = 0.f;
#pragma unroll
  for (int c = 0; c < KC; ++c) {
    float v = xp[(size_t)c * NN];
    s = fmaf(v, v, s);
  }
  h[n] = 0.5f * s;
}

// med3 ripple: insert e into descending top-20 value list (values only).
#define RIP(tv, e)                                   \
  do {                                               \
    float _e = (e);                                  \
    tv[19] = MED3F(tv[18], tv[19], _e);              \
    tv[18] = MED3F(tv[17], tv[18], _e);              \
    tv[17] = MED3F(tv[16], tv[17], _e);              \
    tv[16] = MED3F(tv[15], tv[16], _e);              \
    tv[15] = MED3F(tv[14], tv[15], _e);              \
    tv[14] = MED3F(tv[13], tv[14], _e);              \
    tv[13] = MED3F(tv[12], tv[13], _e);              \
    tv[12] = MED3F(tv[11], tv[12], _e);              \
    tv[11] = MED3F(tv[10], tv[11], _e);              \
    tv[10] = MED3F(tv[9],  tv[10], _e);              \
    tv[9]  = MED3F(tv[8],  tv[9],  _e);              \
    tv[8]  = MED3F(tv[7],  tv[8],  _e);              \
    tv[7]  = MED3F(tv[6],  tv[7],  _e);              \
    tv[6]  = MED3F(tv[5],  tv[6],  _e);              \
    tv[5]  = MED3F(tv[4],  tv[5],  _e);              \
    tv[4]  = MED3F(tv[3],  tv[4],  _e);              \
    tv[3]  = MED3F(tv[2],  tv[3],  _e);              \
    tv[2]  = MED3F(tv[1],  tv[2],  _e);              \
    tv[1]  = MED3F(tv[0],  tv[1],  _e);              \
    tv[0]  = fmaxf(tv[0], _e);                       \
  } while (0)

// Depth-8 value+index ripple (~31 VALU ops). Strict-greater insert +
// ascending-j insertion order = equal values keep the earlier (smaller-j)
// element above -> matches lax.top_k tie behavior. cmps read OLD tv values;
// tv/ti updated bottom-up.
#define RIPX8(tv, ti, e, jj)                                                  \
  do {                                                                        \
    float _e = (e);                                                           \
    int _j = (jj);                                                            \
    bool c0 = _e > tv[0], c1 = _e > tv[1], c2 = _e > tv[2], c3 = _e > tv[3];  \
    bool c4 = _e > tv[4], c5 = _e > tv[5], c6 = _e > tv[6], c7 = _e > tv[7];  \
    tv[7] = MED3F(tv[6], tv[7], _e); ti[7] = c6 ? ti[6] : (c7 ? _j : ti[7]);  \
    tv[6] = MED3F(tv[5], tv[6], _e); ti[6] = c5 ? ti[5] : (c6 ? _j : ti[6]);  \
    tv[5] = MED3F(tv[4], tv[5], _e); ti[5] = c4 ? ti[4] : (c5 ? _j : ti[5]);  \
    tv[4] = MED3F(tv[3], tv[4], _e); ti[4] = c3 ? ti[3] : (c4 ? _j : ti[4]);  \
    tv[3] = MED3F(tv[2], tv[3], _e); ti[3] = c2 ? ti[2] : (c3 ? _j : ti[3]);  \
    tv[2] = MED3F(tv[1], tv[2], _e); ti[2] = c1 ? ti[1] : (c2 ? _j : ti[2]);  \
    tv[1] = MED3F(tv[0], tv[1], _e); ti[1] = c0 ? ti[0] : (c1 ? _j : ti[1]);  \
    tv[0] = fmaxf(tv[0], _e);        ti[0] = c0 ? _j : ti[0];                 \
  } while (0)

// Pair-split distance batch, 8 j's per pair-iteration. Each lane accumulates
// its 29-channel partial for all 8 j's; shfl_xor(1)+add completes the dot
// (commutative fp add -> bit-identical in both lanes). Even lane owns j+0..3,
// odd lane j+4..7 (half4 select). k_fb replicates the summation order
// bit-exactly: s1 = chain(c 0..28), s2 = chain(c 29..57), d = (s1+s2) - h.
#define DIST8P(jq)                                                    \
  float a0 = 0.f, a1 = 0.f, a2 = 0.f, a3 = 0.f;                       \
  float a4 = 0.f, a5 = 0.f, a6 = 0.f, a7 = 0.f;                       \
  _Pragma("unroll")                                                   \
  for (int cc = 0; cc < HC; ++cc) {                                   \
    float4 x0 = *(const float4*)(ltp + cc * 64 + (jq) * 8);           \
    float4 x1 = *(const float4*)(ltp + cc * 64 + (jq) * 8 + 4);       \
    float xic = xi[cc];                                               \
    a0 = fmaf(xic, x0.x, a0); a1 = fmaf(xic, x0.y, a1);               \
    a2 = fmaf(xic, x0.z, a2); a3 = fmaf(xic, x0.w, a3);               \
    a4 = fmaf(xic, x1.x, a4); a5 = fmaf(xic, x1.y, a5);               \
    a6 = fmaf(xic, x1.z, a6); a7 = fmaf(xic, x1.w, a7);               \
  }                                                                   \
  a0 += __shfl_xor(a0, 1); a1 += __shfl_xor(a1, 1);                   \
  a2 += __shfl_xor(a2, 1); a3 += __shfl_xor(a3, 1);                   \
  a4 += __shfl_xor(a4, 1); a5 += __shfl_xor(a5, 1);                   \
  a6 += __shfl_xor(a6, 1); a7 += __shfl_xor(a7, 1);                   \
  float4 hA = *(const float4*)(lh + (jq) * 8 + half4);                \
  float d0 = (half4 ? a4 : a0) - hA.x;                                \
  float d1 = (half4 ? a5 : a1) - hA.y;                                \
  float d2 = (half4 ? a6 : a2) - hA.z;                                \
  float d3 = (half4 ? a7 : a3) - hA.w;

// rows >= HC (odd half) shifted by HPAD words to land on a disjoint bank group.
#define STAGE_TILE(jbase)                                             \
  __syncthreads();                                                    \
  for (int f = t; f < KC * 16; f += 256) {                            \
    int c = f >> 4, q = f & 15;                                       \
    float4 v = *(const float4*)(xb + c * NN + (jbase) + q * 4);       \
    *(float4*)(ltile + c * 64 + q * 4 + (c >= HC ? HPAD : 0)) = v;    \
  }                                                                   \
  if (t < 64) lh[t] = hg[b * NN + (jbase) + t];                       \
  __syncthreads();

// ---------------- single pass: per-(query,split) top-8 values+indices ----------------
// grid: BB(8) x itile(32) x split(8) = 2048 blocks of 256 threads.
// 128 queries per block (lane pairs), pair handles 8 j's per DIST8P.
__global__ __launch_bounds__(256, 4) void k_knnA(const float* __restrict__ x,
                                                 const float* __restrict__ hg,
                                                 float* __restrict__ candvx) {
  __shared__ float ltile[KC * 64 + HPAD];
  __shared__ float lh[64];
  int t = threadIdx.x;
  int l = t & 63;
  int w = t >> 6;
  int half = l & 1;
  int half4 = half * 4;
  int bidx = blockIdx.x;
  int b = bidx >> 8;
  int itile = (bidx >> 3) & 31;
  int split = bidx & 7;
  int i = itile * 128 + w * 32 + (l >> 1);
  const float* xb = x + ((size_t)b * CC + KSKIP) * NN;
  const float* ltp = ltile + half * (HC * 64 + HPAD);

  float xi[HC];
#pragma unroll
  for (int cc = 0; cc < HC; ++cc) xi[cc] = xb[(half * HC + cc) * NN + i];

  float tv[TIDX];
  int ti[TIDX];
#pragma unroll
  for (int s = 0; s < TIDX; ++s) { tv[s] = NEGINF; ti[s] = -1; }

#pragma unroll 1
  for (int jt = 0; jt < JS / 64; ++jt) {
    int jbase = split * JS + jt * 64;
    STAGE_TILE(jbase)
#pragma unroll 1
    for (int jq = 0; jq < 8; ++jq) {
      DIST8P(jq)
      int j0 = jbase + jq * 8 + half4;
      RIPX8(tv, ti, d0, j0 + 0); RIPX8(tv, ti, d1, j0 + 1);
      RIPX8(tv, ti, d2, j0 + 2); RIPX8(tv, ti, d3, j0 + 3);
    }
  }

  // merge partner lane's list (snapshot first: partner's mutates during merge).
  // All 8 partner entries carry real indices -- no poison path at depth 8.
  float ov[TIDX];
  int oi[TIDX];
#pragma unroll
  for (int s = 0; s < TIDX; ++s) ov[s] = __shfl_xor(tv[s], 1);
#pragma unroll
  for (int s = 0; s < TIDX; ++s) oi[s] = __shfl_xor(ti[s], 1);
#pragma unroll
  for (int s = 0; s < TIDX; ++s) { RIPX8(tv, ti, ov[s], oi[s]); }

  if (!half) {
    float* cv = candvx + (((size_t)(b * NN + i)) * NSPLIT + split) * REC;
    *(float4*)(cv + 0) = make_float4(tv[0], tv[1], tv[2], tv[3]);
    *(float4*)(cv + 4) = make_float4(tv[4], tv[5], tv[6], tv[7]);
    int* cvi = (int*)(cv + TIDX);
    *(int4*)(cvi + 0) = make_int4(ti[0], ti[1], ti[2], ti[3]);
    *(int4*)(cvi + 4) = make_int4(ti[4], ti[5], ti[6], ti[7]);
  }
}

// ---------------- final (fused thresh+classify): ----------------
// thr = 20th largest of the 64 tracked values. Exact unless any split's
// 8th tracked value >= thr (hidden qualifier possible) -> fallback list.
// Else: top-20 = all {v > thr} + (20-m) smallest-j ties {v == thr}.
__global__ void k_final(const float* __restrict__ candvx, int* __restrict__ idxk,
                        int* __restrict__ fbl, int* __restrict__ fbcnt) {
  int qi = blockIdx.x * 256 + threadIdx.x;
  const float* cv = candvx + (size_t)qi * NSPLIT * REC;
  float tv[KK];
#pragma unroll
  for (int s = 0; s < KK; ++s) tv[s] = NEGINF;
  float v7max = NEGINF;
#pragma unroll 1
  for (int sp = 0; sp < NSPLIT; ++sp) {
    const float* r = cv + sp * REC;
#pragma unroll
    for (int s = 0; s < TIDX; ++s) { RIP(tv, r[s]); }
    v7max = fmaxf(v7max, r[TIDX - 1]);
  }
  float thr = tv[19];
  int* op = idxk + (size_t)qi * KK;
  int m = 0;
  bool fb = (v7max >= thr);
  if (!fb) {
#pragma unroll 1
    for (int sp = 0; sp < NSPLIT; ++sp) {
      const float* r = cv + sp * REC;
      const int* ri = (const int*)(r + TIDX);
#pragma unroll
      for (int s = 0; s < TIDX; ++s) {
        float v = r[s];
        if (v > thr) {
          if (m < KK) op[m] = ri[s];
          ++m;
        }
      }
    }
    if (m >= KK) fb = true;  // paranoia: no-fire implies m <= 19
  }
  if (fb) {
    int p = atomicAdd(fbcnt, 1);
    fbl[p] = qi;
    return;
  }
  // fill (KK-m) smallest-j ties at v == thr (all such are tracked when no-fire)
  int need = KK - m;
  int last = -1;
#pragma unroll 1
  for (int r2 = 0; r2 < need; ++r2) {
    int best = 0x7fffffff;
#pragma unroll 1
    for (int sp = 0; sp < NSPLIT; ++sp) {
      const float* r = cv + sp * REC;
      const int* ri = (const int*)(r + TIDX);
#pragma unroll
      for (int s = 0; s < TIDX; ++s) {
        if (r[s] == thr) {
          int jx = ri[s];
          if (jx > last && jx < best) best = jx;
        }
      }
    }
    op[m + r2] = best;
    last = best;
  }
}

// ---------------- fallback: exact self-sufficient rescan ----------------
// Per query: pass1 per-thread top-20 (values) over its 16 j's + LDS tree
// merge -> exact thr; pass2 collect (d,j) with d >= thr; serial select.
// d chain matches DIST8P bit-exactly: s1=chain(c0..28), s2=chain(c29..57),
// d = (s1+s2) - h.
__global__ __launch_bounds__(256) void k_fb(const float* __restrict__ x,
                                            const float* __restrict__ hg,
                                            const int* __restrict__ fbl,
                                            const int* __restrict__ fbcnt,
                                            int* __restrict__ idxk) {
  __shared__ float xiA[HC];
  __shared__ float xiB[HC];
  __shared__ float lists[256 * KK];
  __shared__ float db[FBCAP * 2];
  __shared__ int cnt;
  int t = threadIdx.x;
  int nfb = *fbcnt;
  if (nfb > BB * NN) nfb = BB * NN;
#pragma unroll 1
  for (int q = blockIdx.x; q < nfb; q += gridDim.x) {
    int qi = fbl[q];
    int b = qi >> 12;
    int i = qi & (NN - 1);
    const float* xb = x + ((size_t)b * CC + KSKIP) * NN;
    if (t < HC) xiA[t] = xb[t * NN + i];
    else if (t < 2 * HC) xiB[t - HC] = xb[(size_t)t * NN + i];
    if (t == 0) cnt = 0;
    __syncthreads();

    float tv[KK];
#pragma unroll
    for (int s = 0; s < KK; ++s) tv[s] = NEGINF;
#pragma unroll 1
    for (int j = t; j < NN; j += 256) {
      float s1 = 0.f, s2 = 0.f;
#pragma unroll
      for (int cc = 0; cc < HC; ++cc) s1 = fmaf(xiA[cc], xb[cc * NN + j], s1);
#pragma unroll
      for (int cc = 0; cc < HC; ++cc) s2 = fmaf(xiB[cc], xb[(HC + cc) * NN + j], s2);
      float d = (s1 + s2) - hg[b * NN + j];
      RIP(tv, d);
    }
#pragma unroll
    for (int s = 0; s < KK; ++s) lists[t * KK + s] = tv[s];
    __syncthreads();
#pragma unroll 1
    for (int st = 128; st >= 1; st >>= 1) {
      if (t < st) {
#pragma unroll
        for (int s = 0; s < KK; ++s) { RIP(tv, lists[(t + st) * KK + s]); }
#pragma unroll
        for (int s = 0; s < KK; ++s) lists[t * KK + s] = tv[s];
      }
      __syncthreads();
    }
    float thr = lists[KK - 1];
    __syncthreads();  // everyone read thr before lists reuse next query

    // pass2: collect candidates
#pragma unroll 1
    for (int j = t; j < NN; j += 256) {
      float s1 = 0.f, s2 = 0.f;
#pragma unroll
      for (int cc = 0; cc < HC; ++cc) s1 = fmaf(xiA[cc], xb[cc * NN + j], s1);
#pragma unroll
      for (int cc = 0; cc < HC; ++cc) s2 = fmaf(xiB[cc], xb[(HC + cc) * NN + j], s2);
      float d = (s1 + s2) - hg[b * NN + j];
      if (d >= thr) {
        int p = atomicAdd(&cnt, 1);
        if (p < FBCAP) { db[p * 2] = d; db[p * 2 + 1] = __int_as_float(j); }
      }
    }
    __syncthreads();
    if (t == 0) {
      int n = cnt;
      if (n > FBCAP) n = FBCAP;
      int* op = idxk + (size_t)qi * KK;
      int m = 0;
      for (int e = 0; e < n; ++e) {
        if (db[e * 2] > thr) {
          if (m < KK) op[m] = __float_as_int(db[e * 2 + 1]);
          ++m;
        }
      }
      int need = KK - m;
      int last = -1;
      for (int r = 0; r < need; ++r) {
        int best = 0x7fffffff;
        for (int e = 0; e < n; ++e) {
          if (db[e * 2] == thr) {
            int jx = __float_as_int(db[e * 2 + 1]);
            if (jx > last && jx < best) best = jx;
          }
        }
        op[m + r] = best;
        last = best;
      }
    }
    __syncthreads();
  }
}

// ---------------- K2: u = W1^T x, v = (W2-W1)^T x, stored (b, n, o) ----------------
__global__ void k_uv(const float* __restrict__ x, const float* __restrict__ W,
                     float* __restrict__ ut, float* __restrict__ vt) {
  __shared__ float w1[64 * 65];
  __shared__ float wd[64 * 65];
  __shared__ float xs[64 * 72];
  int t = threadIdx.x;
  int b = blockIdx.x >> 6;
  int nbase = (blockIdx.x & 63) * 64;

  for (int f = t; f < 4096; f += 256) {
    int o = f >> 6, c = f & 63;
    float a = W[o * 128 + c];
    float b2 = W[o * 128 + 64 + c];
    w1[c * 65 + o] = a;
    wd[c * 65 + o] = b2 - a;
  }
  for (int f = t; f < 1024; f += 256) {
    int c = f >> 4, q = f & 15;
    float4 v = *(const float4*)(x + ((size_t)b * CC + c) * NN + nbase + q * 4);
    *(float4*)(xs + c * 72 + q * 4) = v;
  }
  __syncthreads();

  int o = t & 63, w = t >> 6;
  float4 au[4], av[4];
#pragma unroll
  for (int nq = 0; nq < 4; ++nq) {
    au[nq] = make_float4(0.f, 0.f, 0.f, 0.f);
    av[nq] = make_float4(0.f, 0.f, 0.f, 0.f);
  }
#pragma unroll 4
  for (int c = 0; c < 64; ++c) {
    float w1v = w1[c * 65 + o];
    float wdv = wd[c * 65 + o];
#pragma unroll
    for (int nq = 0; nq < 4; ++nq) {
      float4 xv = *(const float4*)(xs + c * 72 + w * 16 + nq * 4);
      au[nq].x = fmaf(w1v, xv.x, au[nq].x);
      au[nq].y = fmaf(w1v, xv.y, au[nq].y);
      au[nq].z = fmaf(w1v, xv.z, au[nq].z);
      au[nq].w = fmaf(w1v, xv.w, au[nq].w);
      av[nq].x = fmaf(wdv, xv.x, av[nq].x);
      av[nq].y = fmaf(wdv, xv.y, av[nq].y);
      av[nq].z = fmaf(wdv, xv.z, av[nq].z);
      av[nq].w = fmaf(wdv, xv.w, av[nq].w);
    }
  }
#pragma unroll
  for (int nq = 0; nq < 4; ++nq) {
    int n = nbase + w * 16 + nq * 4;
    size_t base = ((size_t)b * NN + n) * OO + o;
    ut[base + 0 * OO] = au[nq].x;
    ut[base + 1 * OO] = au[nq].y;
    ut[base + 2 * OO] = au[nq].z;
    ut[base + 3 * OO] = au[nq].w;
    vt[base + 0 * OO] = av[nq].x;
    vt[base + 1 * OO] = av[nq].y;
    vt[base + 2 * OO] = av[nq].z;
    vt[base + 3 * OO] = av[nq].w;
  }
}

// ---------------- K3: BN sum / sumsq over all (b,n,k) per channel ----------------
__global__ void k_stats(const float* __restrict__ ut, const float* __restrict__ vt,
                        const int* __restrict__ idxk, float* __restrict__ gsum,
                        float* __restrict__ gsqs) {
  __shared__ float red[2][4][64];
  int t = threadIdx.x;
  int o = t & 63, w = t >> 6;
  int b = blockIdx.x >> 6;
  int nbase = (blockIdx.x & 63) * 64 + w * 16;
  const float* up = ut + (size_t)b * NN * OO;
  float s = 0.f, s2 = 0.f;
#pragma unroll 1
  for (int nn2 = 0; nn2 < 16; ++nn2) {
    int n = nbase + nn2;
    float vv = vt[((size_t)b * NN + n) * OO + o];
    const int* ip = idxk + ((size_t)b * NN + n) * KK;
    int4 q0 = *(const int4*)(ip + 0);
    int4 q1 = *(const int4*)(ip + 4);
    int4 q2 = *(const int4*)(ip + 8);
    int4 q3 = *(const int4*)(ip + 12);
    int4 q4 = *(const int4*)(ip + 16);
#define ACC(j)                                  \
    {                                           \
      float u = up[(size_t)(j) * OO + o];       \
      float yy = u + vv;                        \
      s += yy;                                  \
      s2 = fmaf(yy, yy, s2);                    \
    }
    ACC(q0.x) ACC(q0.y) ACC(q0.z) ACC(q0.w)
    ACC(q1.x) ACC(q1.y) ACC(q1.z) ACC(q1.w)
    ACC(q2.x) ACC(q2.y) ACC(q2.z) ACC(q2.w)
    ACC(q3.x) ACC(q3.y) ACC(q3.z) ACC(q3.w)
    ACC(q4.x) ACC(q4.y) ACC(q4.z) ACC(q4.w)
#undef ACC
  }
  red[0][w][o] = s;
  red[1][w][o] = s2;
  __syncthreads();
  if (w == 0) {
    float ts = red[0][0][o] + red[0][1][o] + red[0][2][o] + red[0][3][o];
    float t2 = red[1][0][o] + red[1][1][o] + red[1][2][o] + red[1][3][o];
    atomicAdd(&gsum[o], ts);
    atomicAdd(&gsqs[o], t2);
  }
}

// ---------------- K4: finalize BN affine ----------------
__global__ void k_bn(const float* __restrict__ gsum, const float* __restrict__ gsqs,
                     const float* __restrict__ gamma, const float* __restrict__ beta,
                     float* __restrict__ AB) {
  int o = threadIdx.x;
  float mean = gsum[o] * (1.f / M_TOTAL);
  float var = gsqs[o] * (1.f / M_TOTAL) - mean * mean;
  float A = gamma[o] / sqrtf(var + BN_EPS);
  AB[o] = A;
  AB[64 + o] = beta[o] - mean * A;
}

// ---------------- K5: normalized + leakyrelu + max over k, transposed store ----------------
__global__ void k_out(const float* __restrict__ ut, const float* __restrict__ vt,
                      const int* __restrict__ idxk, const float* __restrict__ AB,
                      float* __restrict__ outp) {
  __shared__ float lt[64 * 65];
  int t = threadIdx.x;
  int o = t & 63, w = t >> 6;
  int b = blockIdx.x >> 6;
  int nb = (blockIdx.x & 63) * 64;
  float A = AB[o], Bs = AB[64 + o];
  const float* up = ut + (size_t)b * NN * OO;
#pragma unroll 1
  for (int nn2 = 0; nn2 < 16; ++nn2) {
    int nl = w * 16 + nn2;
    int n = nb + nl;
    float vv = vt[((size_t)b * NN + n) * OO + o];
    const int* ip = idxk + ((size_t)b * NN + n) * KK;
    int4 q0 = *(const int4*)(ip + 0);
    int4 q1 = *(const int4*)(ip + 4);
    int4 q2 = *(const int4*)(ip + 8);
    int4 q3 = *(const int4*)(ip + 12);
    int4 q4 = *(const int4*)(ip + 16);
    float m = NEGINF;
#define STEP(j)                                   \
    {                                             \
      float u = up[(size_t)(j) * OO + o];         \
      float y = fmaf(A, u + vv, Bs);              \
      y = fmaxf(y, NEG * y);                      \
      m = fmaxf(m, y);                            \
    }
    STEP(q0.x) STEP(q0.y) STEP(q0.z) STEP(q0.w)
    STEP(q1.x) STEP(q1.y) STEP(q1.z) STEP(q1.w)
    STEP(q2.x) STEP(q2.y) STEP(q2.z) STEP(q2.w)
    STEP(q3.x) STEP(q3.y) STEP(q3.z) STEP(q3.w)
    STEP(q4.x) STEP(q4.y) STEP(q4.z) STEP(q4.w)
#undef STEP
    lt[nl * 65 + o] = m;
  }
  __syncthreads();
  int oo = t >> 2, part = t & 3;
#pragma unroll
  for (int mq = 0; mq < 4; ++mq) {
    int n0 = part * 16 + mq * 4;
    float4 vvv;
    vvv.x = lt[(n0 + 0) * 65 + oo];
    vvv.y = lt[(n0 + 1) * 65 + oo];
    vvv.z = lt[(n0 + 2) * 65 + oo];
    vvv.w = lt[(n0 + 3) * 65 + oo];
    *(float4*)(outp + ((size_t)b * OO + oo) * NN + nb + n0) = vvv;
  }
}

extern "C" void kernel_launch(void* const* d_in, const int* in_sizes, int n_in,
                              void* d_out, int out_size, void* d_ws, size_t ws_size,
                              hipStream_t stream) {
  const float* x = (const float*)d_in[0];
  const float* W = (const float*)d_in[1];
  const float* gamma = (const float*)d_in[2];
  const float* beta = (const float*)d_in[3];
  float* outp = (float*)d_out;
  char* ws = (char*)d_ws;

  const size_t NQ = (size_t)BB * NN;  // 32768 queries
  size_t off = 0;
  float* hg = (float*)(ws + off); off += NQ * 4;                      // 128 KB
  int* idxk = (int*)(ws + off); off += NQ * KK * 4;                   // 2.6 MB
  int* fbcnt = (int*)(ws + off); off += 256;
  int* fbl = (int*)(ws + off); off += NQ * 4;                         // 128 KB
  float* gsum = (float*)(ws + off); off += 256;
  float* gsqs = (float*)(ws + off); off += 256;
  float* AB = (float*)(ws + off); off += 512;
  // overlapped region:
  //  phase 1 (knnA/final/fb): candvx = NQ*8*16*4 = 16.8 MB
  //  phase 2 (uv/stats/out): ut (8MB) + vt (8MB) = 16 MB
  char* region = ws + off;
  float* candvx = (float*)region;                                     // 16.8 MB
  float* ut = (float*)region;                                         // 8 MB
  float* vt = (float*)(region + NQ * OO * 4);                         // 8 MB

  k_sq<<<BB * NN / 256, 256, 0, stream>>>(x, hg);
  k_knnA<<<BB * 32 * NSPLIT, 256, 0, stream>>>(x, hg, candvx);
  hipMemsetAsync(fbcnt, 0, 4, stream);
  k_final<<<BB * NN / 256, 256, 0, stream>>>(candvx, idxk, fbl, fbcnt);
  k_fb<<<256, 256, 0, stream>>>(x, hg, fbl, fbcnt, idxk);
  k_uv<<<BB * 64, 256, 0, stream>>>(x, W, ut, vt);
  hipMemsetAsync(gsum, 0, 512, stream);
  k_stats<<<BB * 64, 256, 0, stream>>>(ut, vt, idxk, gsum, gsqs);
  k_bn<<<1, 64, 0, stream>>>(gsum, gsqs, gamma, beta, AB);
  k_out<<<BB * 64, 256, 0, stream>>>(ut, vt, idxk, AB, outp);
}

// Round 13
// 629.859 us; speedup vs baseline: 1.2894x; 1.2894x over previous
//
#include <hip/hip_runtime.h>
#include <cstdint>
#include <cstddef>

#define BB 8
#define CC 64
#define NN 4096
#define OO 64
#define KK 20
#define KC 58
#define HC 29             // channels per lane (lane-pair split: even 0-28, odd 29-57)
#define KSKIP 6
#define NSPLIT 8
#define JS 512            // j's per split
#define TIDX 8            // tracked depth per split (values AND indices)
#define REC 16            // candvx record: 8 values + 8 indices (words)
#define FBCAP 96
#define BN_EPS 1e-5f
#define NEG 0.2f
#define NEGINF (-3.402823466e38f)
#define M_TOTAL 655360.0f   // B*N*K
// odd-half LDS tile offset: 29*64 words == 0 mod 32 banks -> collides with the
// even half's bank group (r7: SQ_LDS_BANK_CONFLICT 1.2e8 = 37% of cycles).
// Shift odd half by +4 words (r8: conflicts -> 0).
#define HPAD 4

#define MED3F(a, b, c) __builtin_amdgcn_fmed3f((a), (b), (c))

// DEPTH-8 SINGLE-PASS (r12, knnA proven 403us): per-split top-8 values+idx.
// thr_cand = 20th of 8x8=64 tracked values. KEY FACTS:
//  (a) thr_cand <= thr_true ALWAYS (tracked subset of all).
//  (b) if no split's 8th value >= thr_cand (no-fire), every value >= thr_cand
//      is tracked -> thr_cand == thr_true and selection from tracked is exact.
//  (c) if fired (~1.5% of queries): thr_cand is still a valid LOWER bound ->
//      k_fb collects all d >= thr_cand (superset of top-20, E[n]~22) in ONE
//      pass (bit-exact d chain) + exact lexicographic select. (r13: removed
//      r12's 80KB-LDS tree-merge k_fb -- suspected +168us regression.)
// VGPR-CAP MODEL (r0-r5): cap = 256/min_waves_arg; residency halves at alloc
// {64,128,256}. SPILL TRIPWIRE: k_knnA FETCH_SIZE ~31 MB. GBs = spill.

// ---------------- K0: h = 0.5*||x_{6:}||^2 per point ----------------
__global__ void k_sq(const float* __restrict__ x, float* __restrict__ h) {
  int n = blockIdx.x * 256 + threadIdx.x;  // 0 .. BB*NN-1
  int b = n >> 12;
  int nn = n & (NN - 1);
  const float* xp = x + ((size_t)b * CC + KSKIP) * NN + nn;
  float s = 0.f;
#pragma unroll
  for (int c = 0; c < KC; ++c) {
    float v = xp[(size_t)c * NN];
    s = fmaf(v, v, s);
  }
  h[n] = 0.5f * s;
}

// med3 ripple: insert e into descending top-20 value list (values only).
#define RIP(tv, e)                                   \
  do {                                               \
    float _e = (e);                                  \
    tv[19] = MED3F(tv[18], tv[19], _e);              \
    tv[18] = MED3F(tv[17], tv[18], _e);              \
    tv[17] = MED3F(tv[16], tv[17], _e);              \
    tv[16] = MED3F(tv[15], tv[16], _e);              \
    tv[15] = MED3F(tv[14], tv[15], _e);              \
    tv[14] = MED3F(tv[13], tv[14], _e);              \
    tv[13] = MED3F(tv[12], tv[13], _e);              \
    tv[12] = MED3F(tv[11], tv[12], _e);              \
    tv[11] = MED3F(tv[10], tv[11], _e);              \
    tv[10] = MED3F(tv[9],  tv[10], _e);              \
    tv[9]  = MED3F(tv[8],  tv[9],  _e);              \
    tv[8]  = MED3F(tv[7],  tv[8],  _e);              \
    tv[7]  = MED3F(tv[6],  tv[7],  _e);              \
    tv[6]  = MED3F(tv[5],  tv[6],  _e);              \
    tv[5]  = MED3F(tv[4],  tv[5],  _e);              \
    tv[4]  = MED3F(tv[3],  tv[4],  _e);              \
    tv[3]  = MED3F(tv[2],  tv[3],  _e);              \
    tv[2]  = MED3F(tv[1],  tv[2],  _e);              \
    tv[1]  = MED3F(tv[0],  tv[1],  _e);              \
    tv[0]  = fmaxf(tv[0], _e);                       \
  } while (0)

// Depth-8 value+index ripple (~31 VALU ops). Strict-greater insert +
// ascending-j insertion order = equal values keep the earlier (smaller-j)
// element above -> matches lax.top_k tie behavior. cmps read OLD tv values;
// tv/ti updated bottom-up.
#define RIPX8(tv, ti, e, jj)                                                  \
  do {                                                                        \
    float _e = (e);                                                           \
    int _j = (jj);                                                            \
    bool c0 = _e > tv[0], c1 = _e > tv[1], c2 = _e > tv[2], c3 = _e > tv[3];  \
    bool c4 = _e > tv[4], c5 = _e > tv[5], c6 = _e > tv[6], c7 = _e > tv[7];  \
    tv[7] = MED3F(tv[6], tv[7], _e); ti[7] = c6 ? ti[6] : (c7 ? _j : ti[7]);  \
    tv[6] = MED3F(tv[5], tv[6], _e); ti[6] = c5 ? ti[5] : (c6 ? _j : ti[6]);  \
    tv[5] = MED3F(tv[4], tv[5], _e); ti[5] = c4 ? ti[4] : (c5 ? _j : ti[5]);  \
    tv[4] = MED3F(tv[3], tv[4], _e); ti[4] = c3 ? ti[3] : (c4 ? _j : ti[4]);  \
    tv[3] = MED3F(tv[2], tv[3], _e); ti[3] = c2 ? ti[2] : (c3 ? _j : ti[3]);  \
    tv[2] = MED3F(tv[1], tv[2], _e); ti[2] = c1 ? ti[1] : (c2 ? _j : ti[2]);  \
    tv[1] = MED3F(tv[0], tv[1], _e); ti[1] = c0 ? ti[0] : (c1 ? _j : ti[1]);  \
    tv[0] = fmaxf(tv[0], _e);        ti[0] = c0 ? _j : ti[0];                 \
  } while (0)

// Pair-split distance batch, 8 j's per pair-iteration. Each lane accumulates
// its 29-channel partial for all 8 j's; shfl_xor(1)+add completes the dot
// (commutative fp add -> bit-identical in both lanes). Even lane owns j+0..3,
// odd lane j+4..7 (half4 select). k_fb replicates the summation order
// bit-exactly: s1 = chain(c 0..28), s2 = chain(c 29..57), d = (s1+s2) - h.
#define DIST8P(jq)                                                    \
  float a0 = 0.f, a1 = 0.f, a2 = 0.f, a3 = 0.f;                       \
  float a4 = 0.f, a5 = 0.f, a6 = 0.f, a7 = 0.f;                       \
  _Pragma("unroll")                                                   \
  for (int cc = 0; cc < HC; ++cc) {                                   \
    float4 x0 = *(const float4*)(ltp + cc * 64 + (jq) * 8);           \
    float4 x1 = *(const float4*)(ltp + cc * 64 + (jq) * 8 + 4);       \
    float xic = xi[cc];                                               \
    a0 = fmaf(xic, x0.x, a0); a1 = fmaf(xic, x0.y, a1);               \
    a2 = fmaf(xic, x0.z, a2); a3 = fmaf(xic, x0.w, a3);               \
    a4 = fmaf(xic, x1.x, a4); a5 = fmaf(xic, x1.y, a5);               \
    a6 = fmaf(xic, x1.z, a6); a7 = fmaf(xic, x1.w, a7);               \
  }                                                                   \
  a0 += __shfl_xor(a0, 1); a1 += __shfl_xor(a1, 1);                   \
  a2 += __shfl_xor(a2, 1); a3 += __shfl_xor(a3, 1);                   \
  a4 += __shfl_xor(a4, 1); a5 += __shfl_xor(a5, 1);                   \
  a6 += __shfl_xor(a6, 1); a7 += __shfl_xor(a7, 1);                   \
  float4 hA = *(const float4*)(lh + (jq) * 8 + half4);                \
  float d0 = (half4 ? a4 : a0) - hA.x;                                \
  float d1 = (half4 ? a5 : a1) - hA.y;                                \
  float d2 = (half4 ? a6 : a2) - hA.z;                                \
  float d3 = (half4 ? a7 : a3) - hA.w;

// rows >= HC (odd half) shifted by HPAD words to land on a disjoint bank group.
#define STAGE_TILE(jbase)                                             \
  __syncthreads();                                                    \
  for (int f = t; f < KC * 16; f += 256) {                            \
    int c = f >> 4, q = f & 15;                                       \
    float4 v = *(const float4*)(xb + c * NN + (jbase) + q * 4);       \
    *(float4*)(ltile + c * 64 + q * 4 + (c >= HC ? HPAD : 0)) = v;    \
  }                                                                   \
  if (t < 64) lh[t] = hg[b * NN + (jbase) + t];                       \
  __syncthreads();

// ---------------- single pass: per-(query,split) top-8 values+indices ----------------
// grid: BB(8) x itile(32) x split(8) = 2048 blocks of 256 threads.
// 128 queries per block (lane pairs), pair handles 8 j's per DIST8P.
__global__ __launch_bounds__(256, 4) void k_knnA(const float* __restrict__ x,
                                                 const float* __restrict__ hg,
                                                 float* __restrict__ candvx) {
  __shared__ float ltile[KC * 64 + HPAD];
  __shared__ float lh[64];
  int t = threadIdx.x;
  int l = t & 63;
  int w = t >> 6;
  int half = l & 1;
  int half4 = half * 4;
  int bidx = blockIdx.x;
  int b = bidx >> 8;
  int itile = (bidx >> 3) & 31;
  int split = bidx & 7;
  int i = itile * 128 + w * 32 + (l >> 1);
  const float* xb = x + ((size_t)b * CC + KSKIP) * NN;
  const float* ltp = ltile + half * (HC * 64 + HPAD);

  float xi[HC];
#pragma unroll
  for (int cc = 0; cc < HC; ++cc) xi[cc] = xb[(half * HC + cc) * NN + i];

  float tv[TIDX];
  int ti[TIDX];
#pragma unroll
  for (int s = 0; s < TIDX; ++s) { tv[s] = NEGINF; ti[s] = -1; }

#pragma unroll 1
  for (int jt = 0; jt < JS / 64; ++jt) {
    int jbase = split * JS + jt * 64;
    STAGE_TILE(jbase)
#pragma unroll 1
    for (int jq = 0; jq < 8; ++jq) {
      DIST8P(jq)
      int j0 = jbase + jq * 8 + half4;
      RIPX8(tv, ti, d0, j0 + 0); RIPX8(tv, ti, d1, j0 + 1);
      RIPX8(tv, ti, d2, j0 + 2); RIPX8(tv, ti, d3, j0 + 3);
    }
  }

  // merge partner lane's list (snapshot first: partner's mutates during merge).
  float ov[TIDX];
  int oi[TIDX];
#pragma unroll
  for (int s = 0; s < TIDX; ++s) ov[s] = __shfl_xor(tv[s], 1);
#pragma unroll
  for (int s = 0; s < TIDX; ++s) oi[s] = __shfl_xor(ti[s], 1);
#pragma unroll
  for (int s = 0; s < TIDX; ++s) { RIPX8(tv, ti, ov[s], oi[s]); }

  if (!half) {
    float* cv = candvx + (((size_t)(b * NN + i)) * NSPLIT + split) * REC;
    *(float4*)(cv + 0) = make_float4(tv[0], tv[1], tv[2], tv[3]);
    *(float4*)(cv + 4) = make_float4(tv[4], tv[5], tv[6], tv[7]);
    int* cvi = (int*)(cv + TIDX);
    *(int4*)(cvi + 0) = make_int4(ti[0], ti[1], ti[2], ti[3]);
    *(int4*)(cvi + 4) = make_int4(ti[4], ti[5], ti[6], ti[7]);
  }
}

// ---------------- final (fused thresh+classify) ----------------
// thr = 20th largest of the 64 tracked values (always <= thr_true).
// No-fire (all splits' 8th value < thr): selection from tracked is exact.
// Fire: store query in fbl; k_fb re-collects with thr as a lower bound.
__global__ void k_final(const float* __restrict__ candvx, int* __restrict__ idxk,
                        float* __restrict__ thrv, int* __restrict__ fbl,
                        int* __restrict__ fbcnt) {
  int qi = blockIdx.x * 256 + threadIdx.x;
  const float* cv = candvx + (size_t)qi * NSPLIT * REC;
  float tv[KK];
#pragma unroll
  for (int s = 0; s < KK; ++s) tv[s] = NEGINF;
  float v7max = NEGINF;
#pragma unroll 1
  for (int sp = 0; sp < NSPLIT; ++sp) {
    const float* r = cv + sp * REC;
#pragma unroll
    for (int s = 0; s < TIDX; ++s) { RIP(tv, r[s]); }
    v7max = fmaxf(v7max, r[TIDX - 1]);
  }
  float thr = tv[19];
  thrv[qi] = thr;
  int* op = idxk + (size_t)qi * KK;
  int m = 0;
  bool fb = (v7max >= thr);
  if (!fb) {
#pragma unroll 1
    for (int sp = 0; sp < NSPLIT; ++sp) {
      const float* r = cv + sp * REC;
      const int* ri = (const int*)(r + TIDX);
#pragma unroll
      for (int s = 0; s < TIDX; ++s) {
        float v = r[s];
        if (v > thr) {
          if (m < KK) op[m] = ri[s];
          ++m;
        }
      }
    }
    if (m >= KK) fb = true;  // paranoia: no-fire implies m <= 19
  }
  if (fb) {
    int p = atomicAdd(fbcnt, 1);
    fbl[p] = qi;
    return;
  }
  // fill (KK-m) smallest-j ties at v == thr (all such are tracked when no-fire)
  int need = KK - m;
  int last = -1;
#pragma unroll 1
  for (int r2 = 0; r2 < need; ++r2) {
    int best = 0x7fffffff;
#pragma unroll 1
    for (int sp = 0; sp < NSPLIT; ++sp) {
      const float* r = cv + sp * REC;
      const int* ri = (const int*)(r + TIDX);
#pragma unroll
      for (int s = 0; s < TIDX; ++s) {
        if (r[s] == thr) {
          int jx = ri[s];
          if (jx > last && jx < best) best = jx;
        }
      }
    }
    op[m + r2] = best;
    last = best;
  }
}

// ---------------- fallback: single-pass collect + exact lexicographic select ----
// thr (from k_final) is a LOWER bound on the true 20th value -> {d >= thr}
// is a superset of the top-20 (E[n] ~ 22). One distance pass (chain matches
// DIST8P bit-exactly), then t0 selects top-20 by (d desc, j asc).
__global__ __launch_bounds__(256) void k_fb(const float* __restrict__ x,
                                            const float* __restrict__ hg,
                                            const float* __restrict__ thrv,
                                            const int* __restrict__ fbl,
                                            const int* __restrict__ fbcnt,
                                            int* __restrict__ idxk) {
  __shared__ float xiA[HC];
  __shared__ float xiB[HC];
  __shared__ float db[FBCAP * 2];
  __shared__ int cnt;
  int t = threadIdx.x;
  int nfb = *fbcnt;
  if (nfb > BB * NN) nfb = BB * NN;
#pragma unroll 1
  for (int q = blockIdx.x; q < nfb; q += gridDim.x) {
    int qi = fbl[q];
    int b = qi >> 12;
    int i = qi & (NN - 1);
    const float* xb = x + ((size_t)b * CC + KSKIP) * NN;
    if (t < HC) xiA[t] = xb[t * NN + i];
    else if (t < 2 * HC) xiB[t - HC] = xb[(size_t)t * NN + i];
    if (t == 0) cnt = 0;
    __syncthreads();
    float thr = thrv[qi];
#pragma unroll 1
    for (int j = t; j < NN; j += 256) {
      float s1 = 0.f, s2 = 0.f;
#pragma unroll
      for (int cc = 0; cc < HC; ++cc) s1 = fmaf(xiA[cc], xb[cc * NN + j], s1);
#pragma unroll
      for (int cc = 0; cc < HC; ++cc) s2 = fmaf(xiB[cc], xb[(HC + cc) * NN + j], s2);
      float d = (s1 + s2) - hg[b * NN + j];
      if (d >= thr) {
        int p = atomicAdd(&cnt, 1);
        if (p < FBCAP) { db[p * 2] = d; db[p * 2 + 1] = __int_as_float(j); }
      }
    }
    __syncthreads();
    if (t == 0) {
      int n = cnt;
      if (n > FBCAP) n = FBCAP;
      int* op = idxk + (size_t)qi * KK;
      // exact top-20 by (d desc, j asc): repeated max-scan, consume by -inf
      for (int r = 0; r < KK; ++r) {
        float bd = NEGINF;
        int bj = 0x7fffffff;
        int be = -1;
        for (int e = 0; e < n; ++e) {
          float d = db[e * 2];
          int jx = __float_as_int(db[e * 2 + 1]);
          if (d > bd || (d == bd && jx < bj)) { bd = d; bj = jx; be = e; }
        }
        op[r] = bj;
        if (be >= 0) db[be * 2] = NEGINF;
      }
    }
    __syncthreads();
  }
}

// ---------------- K2: u = W1^T x, v = (W2-W1)^T x, stored (b, n, o) ----------------
__global__ void k_uv(const float* __restrict__ x, const float* __restrict__ W,
                     float* __restrict__ ut, float* __restrict__ vt) {
  __shared__ float w1[64 * 65];
  __shared__ float wd[64 * 65];
  __shared__ float xs[64 * 72];
  int t = threadIdx.x;
  int b = blockIdx.x >> 6;
  int nbase = (blockIdx.x & 63) * 64;

  for (int f = t; f < 4096; f += 256) {
    int o = f >> 6, c = f & 63;
    float a = W[o * 128 + c];
    float b2 = W[o * 128 + 64 + c];
    w1[c * 65 + o] = a;
    wd[c * 65 + o] = b2 - a;
  }
  for (int f = t; f < 1024; f += 256) {
    int c = f >> 4, q = f & 15;
    float4 v = *(const float4*)(x + ((size_t)b * CC + c) * NN + nbase + q * 4);
    *(float4*)(xs + c * 72 + q * 4) = v;
  }
  __syncthreads();

  int o = t & 63, w = t >> 6;
  float4 au[4], av[4];
#pragma unroll
  for (int nq = 0; nq < 4; ++nq) {
    au[nq] = make_float4(0.f, 0.f, 0.f, 0.f);
    av[nq] = make_float4(0.f, 0.f, 0.f, 0.f);
  }
#pragma unroll 4
  for (int c = 0; c < 64; ++c) {
    float w1v = w1[c * 65 + o];
    float wdv = wd[c * 65 + o];
#pragma unroll
    for (int nq = 0; nq < 4; ++nq) {
      float4 xv = *(const float4*)(xs + c * 72 + w * 16 + nq * 4);
      au[nq].x = fmaf(w1v, xv.x, au[nq].x);
      au[nq].y = fmaf(w1v, xv.y, au[nq].y);
      au[nq].z = fmaf(w1v, xv.z, au[nq].z);
      au[nq].w = fmaf(w1v, xv.w, au[nq].w);
      av[nq].x = fmaf(wdv, xv.x, av[nq].x);
      av[nq].y = fmaf(wdv, xv.y, av[nq].y);
      av[nq].z = fmaf(wdv, xv.z, av[nq].z);
      av[nq].w = fmaf(wdv, xv.w, av[nq].w);
    }
  }
#pragma unroll
  for (int nq = 0; nq < 4; ++nq) {
    int n = nbase + w * 16 + nq * 4;
    size_t base = ((size_t)b * NN + n) * OO + o;
    ut[base + 0 * OO] = au[nq].x;
    ut[base + 1 * OO] = au[nq].y;
    ut[base + 2 * OO] = au[nq].z;
    ut[base + 3 * OO] = au[nq].w;
    vt[base + 0 * OO] = av[nq].x;
    vt[base + 1 * OO] = av[nq].y;
    vt[base + 2 * OO] = av[nq].z;
    vt[base + 3 * OO] = av[nq].w;
  }
}

// ---------------- K3: BN sum / sumsq over all (b,n,k) per channel ----------------
__global__ void k_stats(const float* __restrict__ ut, const float* __restrict__ vt,
                        const int* __restrict__ idxk, float* __restrict__ gsum,
                        float* __restrict__ gsqs) {
  __shared__ float red[2][4][64];
  int t = threadIdx.x;
  int o = t & 63, w = t >> 6;
  int b = blockIdx.x >> 6;
  int nbase = (blockIdx.x & 63) * 64 + w * 16;
  const float* up = ut + (size_t)b * NN * OO;
  float s = 0.f, s2 = 0.f;
#pragma unroll 1
  for (int nn2 = 0; nn2 < 16; ++nn2) {
    int n = nbase + nn2;
    float vv = vt[((size_t)b * NN + n) * OO + o];
    const int* ip = idxk + ((size_t)b * NN + n) * KK;
    int4 q0 = *(const int4*)(ip + 0);
    int4 q1 = *(const int4*)(ip + 4);
    int4 q2 = *(const int4*)(ip + 8);
    int4 q3 = *(const int4*)(ip + 12);
    int4 q4 = *(const int4*)(ip + 16);
#define ACC(j)                                  \
    {                                           \
      float u = up[(size_t)(j) * OO + o];       \
      float yy = u + vv;                        \
      s += yy;                                  \
      s2 = fmaf(yy, yy, s2);                    \
    }
    ACC(q0.x) ACC(q0.y) ACC(q0.z) ACC(q0.w)
    ACC(q1.x) ACC(q1.y) ACC(q1.z) ACC(q1.w)
    ACC(q2.x) ACC(q2.y) ACC(q2.z) ACC(q2.w)
    ACC(q3.x) ACC(q3.y) ACC(q3.z) ACC(q3.w)
    ACC(q4.x) ACC(q4.y) ACC(q4.z) ACC(q4.w)
#undef ACC
  }
  red[0][w][o] = s;
  red[1][w][o] = s2;
  __syncthreads();
  if (w == 0) {
    float ts = red[0][0][o] + red[0][1][o] + red[0][2][o] + red[0][3][o];
    float t2 = red[1][0][o] + red[1][1][o] + red[1][2][o] + red[1][3][o];
    atomicAdd(&gsum[o], ts);
    atomicAdd(&gsqs[o], t2);
  }
}

// ---------------- K4: finalize BN affine ----------------
__global__ void k_bn(const float* __restrict__ gsum, const float* __restrict__ gsqs,
                     const float* __restrict__ gamma, const float* __restrict__ beta,
                     float* __restrict__ AB) {
  int o = threadIdx.x;
  float mean = gsum[o] * (1.f / M_TOTAL);
  float var = gsqs[o] * (1.f / M_TOTAL) - mean * mean;
  float A = gamma[o] / sqrtf(var + BN_EPS);
  AB[o] = A;
  AB[64 + o] = beta[o] - mean * A;
}

// ---------------- K5: normalized + leakyrelu + max over k, transposed store ----------------
__global__ void k_out(const float* __restrict__ ut, const float* __restrict__ vt,
                      const int* __restrict__ idxk, const float* __restrict__ AB,
                      float* __restrict__ outp) {
  __shared__ float lt[64 * 65];
  int t = threadIdx.x;
  int o = t & 63, w = t >> 6;
  int b = blockIdx.x >> 6;
  int nb = (blockIdx.x & 63) * 64;
  float A = AB[o], Bs = AB[64 + o];
  const float* up = ut + (size_t)b * NN * OO;
#pragma unroll 1
  for (int nn2 = 0; nn2 < 16; ++nn2) {
    int nl = w * 16 + nn2;
    int n = nb + nl;
    float vv = vt[((size_t)b * NN + n) * OO + o];
    const int* ip = idxk + ((size_t)b * NN + n) * KK;
    int4 q0 = *(const int4*)(ip + 0);
    int4 q1 = *(const int4*)(ip + 4);
    int4 q2 = *(const int4*)(ip + 8);
    int4 q3 = *(const int4*)(ip + 12);
    int4 q4 = *(const int4*)(ip + 16);
    float m = NEGINF;
#define STEP(j)                                   \
    {                                             \
      float u = up[(size_t)(j) * OO + o];         \
      float y = fmaf(A, u + vv, Bs);              \
      y = fmaxf(y, NEG * y);                      \
      m = fmaxf(m, y);                            \
    }
    STEP(q0.x) STEP(q0.y) STEP(q0.z) STEP(q0.w)
    STEP(q1.x) STEP(q1.y) STEP(q1.z) STEP(q1.w)
    STEP(q2.x) STEP(q2.y) STEP(q2.z) STEP(q2.w)
    STEP(q3.x) STEP(q3.y) STEP(q3.z) STEP(q3.w)
    STEP(q4.x) STEP(q4.y) STEP(q4.z) STEP(q4.w)
#undef STEP
    lt[nl * 65 + o] = m;
  }
  __syncthreads();
  int oo = t >> 2, part = t & 3;
#pragma unroll
  for (int mq = 0; mq < 4; ++mq) {
    int n0 = part * 16 + mq * 4;
    float4 vvv;
    vvv.x = lt[(n0 + 0) * 65 + oo];
    vvv.y = lt[(n0 + 1) * 65 + oo];
    vvv.z = lt[(n0 + 2) * 65 + oo];
    vvv.w = lt[(n0 + 3) * 65 + oo];
    *(float4*)(outp + ((size_t)b * OO + oo) * NN + nb + n0) = vvv;
  }
}

extern "C" void kernel_launch(void* const* d_in, const int* in_sizes, int n_in,
                              void* d_out, int out_size, void* d_ws, size_t ws_size,
                              hipStream_t stream) {
  const float* x = (const float*)d_in[0];
  const float* W = (const float*)d_in[1];
  const float* gamma = (const float*)d_in[2];
  const float* beta = (const float*)d_in[3];
  float* outp = (float*)d_out;
  char* ws = (char*)d_ws;

  const size_t NQ = (size_t)BB * NN;  // 32768 queries
  size_t off = 0;
  float* hg = (float*)(ws + off); off += NQ * 4;                      // 128 KB
  float* thrv = (float*)(ws + off); off += NQ * 4;                    // 128 KB
  int* idxk = (int*)(ws + off); off += NQ * KK * 4;                   // 2.6 MB
  int* fbcnt = (int*)(ws + off); off += 256;
  int* fbl = (int*)(ws + off); off += NQ * 4;                         // 128 KB
  float* gsum = (float*)(ws + off); off += 256;
  float* gsqs = (float*)(ws + off); off += 256;
  float* AB = (float*)(ws + off); off += 512;
  // overlapped region:
  //  phase 1 (knnA/final/fb): candvx = NQ*8*16*4 = 16.8 MB
  //  phase 2 (uv/stats/out): ut (8MB) + vt (8MB) = 16 MB
  char* region = ws + off;
  float* candvx = (float*)region;                                     // 16.8 MB
  float* ut = (float*)region;                                         // 8 MB
  float* vt = (float*)(region + NQ * OO * 4);                         // 8 MB

  k_sq<<<BB * NN / 256, 256, 0, stream>>>(x, hg);
  k_knnA<<<BB * 32 * NSPLIT, 256, 0, stream>>>(x, hg, candvx);
  hipMemsetAsync(fbcnt, 0, 4, stream);
  k_final<<<BB * NN / 256, 256, 0, stream>>>(candvx, idxk, thrv, fbl, fbcnt);
  k_fb<<<256, 256, 0, stream>>>(x, hg, thrv, fbl, fbcnt, idxk);
  k_uv<<<BB * 64, 256, 0, stream>>>(x, W, ut, vt);
  hipMemsetAsync(gsum, 0, 512, stream);
  k_stats<<<BB * 64, 256, 0, stream>>>(ut, vt, idxk, gsum, gsqs);
  k_bn<<<1, 64, 0, stream>>>(gsum, gsqs, gamma, beta, AB);
  k_out<<<BB * 64, 256, 0, stream>>>(ut, vt, idxk, AB, outp);
}

// Round 14
// 624.456 us; speedup vs baseline: 1.3006x; 1.0087x over previous
//
#include <hip/hip_runtime.h>
#include <cstdint>
#include <cstddef>

#define BB 8
#define CC 64
#define NN 4096
#define OO 64
#define KK 20
#define KC 58
#define HC 29             // channels per lane (lane-pair split: even 0-28, odd 29-57)
#define KSKIP 6
#define NSPLIT 8
#define JS 512            // j's per split
#define TIDX 8            // tracked depth per split (values AND indices)
#define NQ2 32768         // BB*NN
#define FBCAP 96
#define BN_EPS 1e-5f
#define NEG 0.2f
#define NEGINF (-3.402823466e38f)
#define M_TOTAL 655360.0f   // B*N*K
// odd-half LDS tile offset: 29*64 words == 0 mod 32 banks -> collides with the
// even half's bank group (r7: SQ_LDS_BANK_CONFLICT 1.2e8 = 37% of cycles).
// Shift odd half by +4 words (r8: conflicts -> 0).
#define HPAD 4

#define MED3F(a, b, c) __builtin_amdgcn_fmed3f((a), (b), (c))

// DEPTH-8 SINGLE-PASS (r12/r13, proven: knnA 403us, total 630us):
// per-split top-8 values+idx; thr = 20th of 64 tracked values (<= thr_true
// always); no-fire => exact; fire (~1.5%) => k_fb one-pass collect with thr
// as lower bound + exact select.
// r14 (downstream only; knnA hot loop untouched):
//  - candvx transposed to plane-major [word 0..15][split][qi]: k_final reads
//    become lane-coalesced (old row-major record = 512B/thread stride).
//  - k_sq/k_final: 64-thread blocks x 512 (128x256 left half the CUs idle).
//  - k_stats additionally tracks mx = max_k(u+v) per (n,o) (monotone-rounding
//    argument: fmaf(A,.,B) and leakyrelu are monotone for A>=0, so
//    max(lrelu(A*yy+B)) == lrelu(A*max(yy)+B) BIT-EXACTLY); k_out becomes
//    elementwise on mxv with an exec-masked exact gather fallback for A<0.
// VGPR-CAP MODEL (r0-r5): cap = 256/min_waves_arg; residency halves at alloc
// {64,128,256}. SPILL TRIPWIRE: k_knnA FETCH_SIZE ~30 MB. GBs = spill.

// ---------------- K0: h = 0.5*||x_{6:}||^2 per point ----------------
__global__ void k_sq(const float* __restrict__ x, float* __restrict__ h) {
  int n = blockIdx.x * 64 + threadIdx.x;  // 0 .. BB*NN-1
  int b = n >> 12;
  int nn = n & (NN - 1);
  const float* xp = x + ((size_t)b * CC + KSKIP) * NN + nn;
  float s = 0.f;
#pragma unroll
  for (int c = 0; c < KC; ++c) {
    float v = xp[(size_t)c * NN];
    s = fmaf(v, v, s);
  }
  h[n] = 0.5f * s;
}

// med3 ripple: insert e into descending top-20 value list (values only).
#define RIP(tv, e)                                   \
  do {                                               \
    float _e = (e);                                  \
    tv[19] = MED3F(tv[18], tv[19], _e);              \
    tv[18] = MED3F(tv[17], tv[18], _e);              \
    tv[17] = MED3F(tv[16], tv[17], _e);              \
    tv[16] = MED3F(tv[15], tv[16], _e);              \
    tv[15] = MED3F(tv[14], tv[15], _e);              \
    tv[14] = MED3F(tv[13], tv[14], _e);              \
    tv[13] = MED3F(tv[12], tv[13], _e);              \
    tv[12] = MED3F(tv[11], tv[12], _e);              \
    tv[11] = MED3F(tv[10], tv[11], _e);              \
    tv[10] = MED3F(tv[9],  tv[10], _e);              \
    tv[9]  = MED3F(tv[8],  tv[9],  _e);              \
    tv[8]  = MED3F(tv[7],  tv[8],  _e);              \
    tv[7]  = MED3F(tv[6],  tv[7],  _e);              \
    tv[6]  = MED3F(tv[5],  tv[6],  _e);              \
    tv[5]  = MED3F(tv[4],  tv[5],  _e);              \
    tv[4]  = MED3F(tv[3],  tv[4],  _e);              \
    tv[3]  = MED3F(tv[2],  tv[3],  _e);              \
    tv[2]  = MED3F(tv[1],  tv[2],  _e);              \
    tv[1]  = MED3F(tv[0],  tv[1],  _e);              \
    tv[0]  = fmaxf(tv[0], _e);                       \
  } while (0)

// Depth-8 value+index ripple (~31 VALU ops). Strict-greater insert +
// ascending-j insertion order = equal values keep the earlier (smaller-j)
// element above -> matches lax.top_k tie behavior. cmps read OLD tv values;
// tv/ti updated bottom-up.
#define RIPX8(tv, ti, e, jj)                                                  \
  do {                                                                        \
    float _e = (e);                                                           \
    int _j = (jj);                                                            \
    bool c0 = _e > tv[0], c1 = _e > tv[1], c2 = _e > tv[2], c3 = _e > tv[3];  \
    bool c4 = _e > tv[4], c5 = _e > tv[5], c6 = _e > tv[6], c7 = _e > tv[7];  \
    tv[7] = MED3F(tv[6], tv[7], _e); ti[7] = c6 ? ti[6] : (c7 ? _j : ti[7]);  \
    tv[6] = MED3F(tv[5], tv[6], _e); ti[6] = c5 ? ti[5] : (c6 ? _j : ti[6]);  \
    tv[5] = MED3F(tv[4], tv[5], _e); ti[5] = c4 ? ti[4] : (c5 ? _j : ti[5]);  \
    tv[4] = MED3F(tv[3], tv[4], _e); ti[4] = c3 ? ti[3] : (c4 ? _j : ti[4]);  \
    tv[3] = MED3F(tv[2], tv[3], _e); ti[3] = c2 ? ti[2] : (c3 ? _j : ti[3]);  \
    tv[2] = MED3F(tv[1], tv[2], _e); ti[2] = c1 ? ti[1] : (c2 ? _j : ti[2]);  \
    tv[1] = MED3F(tv[0], tv[1], _e); ti[1] = c0 ? ti[0] : (c1 ? _j : ti[1]);  \
    tv[0] = fmaxf(tv[0], _e);        ti[0] = c0 ? _j : ti[0];                 \
  } while (0)

// Pair-split distance batch, 8 j's per pair-iteration. Each lane accumulates
// its 29-channel partial for all 8 j's; shfl_xor(1)+add completes the dot
// (commutative fp add -> bit-identical in both lanes). Even lane owns j+0..3,
// odd lane j+4..7 (half4 select). k_fb replicates the summation order
// bit-exactly: s1 = chain(c 0..28), s2 = chain(c 29..57), d = (s1+s2) - h.
#define DIST8P(jq)                                                    \
  float a0 = 0.f, a1 = 0.f, a2 = 0.f, a3 = 0.f;                       \
  float a4 = 0.f, a5 = 0.f, a6 = 0.f, a7 = 0.f;                       \
  _Pragma("unroll")                                                   \
  for (int cc = 0; cc < HC; ++cc) {                                   \
    float4 x0 = *(const float4*)(ltp + cc * 64 + (jq) * 8);           \
    float4 x1 = *(const float4*)(ltp + cc * 64 + (jq) * 8 + 4);       \
    float xic = xi[cc];                                               \
    a0 = fmaf(xic, x0.x, a0); a1 = fmaf(xic, x0.y, a1);               \
    a2 = fmaf(xic, x0.z, a2); a3 = fmaf(xic, x0.w, a3);               \
    a4 = fmaf(xic, x1.x, a4); a5 = fmaf(xic, x1.y, a5);               \
    a6 = fmaf(xic, x1.z, a6); a7 = fmaf(xic, x1.w, a7);               \
  }                                                                   \
  a0 += __shfl_xor(a0, 1); a1 += __shfl_xor(a1, 1);                   \
  a2 += __shfl_xor(a2, 1); a3 += __shfl_xor(a3, 1);                   \
  a4 += __shfl_xor(a4, 1); a5 += __shfl_xor(a5, 1);                   \
  a6 += __shfl_xor(a6, 1); a7 += __shfl_xor(a7, 1);                   \
  float4 hA = *(const float4*)(lh + (jq) * 8 + half4);                \
  float d0 = (half4 ? a4 : a0) - hA.x;                                \
  float d1 = (half4 ? a5 : a1) - hA.y;                                \
  float d2 = (half4 ? a6 : a2) - hA.z;                                \
  float d3 = (half4 ? a7 : a3) - hA.w;

// rows >= HC (odd half) shifted by HPAD words to land on a disjoint bank group.
#define STAGE_TILE(jbase)                                             \
  __syncthreads();                                                    \
  for (int f = t; f < KC * 16; f += 256) {                            \
    int c = f >> 4, q = f & 15;                                       \
    float4 v = *(const float4*)(xb + c * NN + (jbase) + q * 4);       \
    *(float4*)(ltile + c * 64 + q * 4 + (c >= HC ? HPAD : 0)) = v;    \
  }                                                                   \
  if (t < 64) lh[t] = hg[b * NN + (jbase) + t];                       \
  __syncthreads();

// candvx plane-major layout: word plane p (0..7 = value s, 8..15 = index s-8),
// then split, then qi. Plane stride = NSPLIT*NQ2 words.
#define PLANE ((size_t)NSPLIT * NQ2)

// ---------------- single pass: per-(query,split) top-8 values+indices ----------------
// grid: BB(8) x itile(32) x split(8) = 2048 blocks of 256 threads.
__global__ __launch_bounds__(256, 4) void k_knnA(const float* __restrict__ x,
                                                 const float* __restrict__ hg,
                                                 float* __restrict__ candvx) {
  __shared__ float ltile[KC * 64 + HPAD];
  __shared__ float lh[64];
  int t = threadIdx.x;
  int l = t & 63;
  int w = t >> 6;
  int half = l & 1;
  int half4 = half * 4;
  int bidx = blockIdx.x;
  int b = bidx >> 8;
  int itile = (bidx >> 3) & 31;
  int split = bidx & 7;
  int i = itile * 128 + w * 32 + (l >> 1);
  const float* xb = x + ((size_t)b * CC + KSKIP) * NN;
  const float* ltp = ltile + half * (HC * 64 + HPAD);

  float xi[HC];
#pragma unroll
  for (int cc = 0; cc < HC; ++cc) xi[cc] = xb[(half * HC + cc) * NN + i];

  float tv[TIDX];
  int ti[TIDX];
#pragma unroll
  for (int s = 0; s < TIDX; ++s) { tv[s] = NEGINF; ti[s] = -1; }

#pragma unroll 1
  for (int jt = 0; jt < JS / 64; ++jt) {
    int jbase = split * JS + jt * 64;
    STAGE_TILE(jbase)
#pragma unroll 1
    for (int jq = 0; jq < 8; ++jq) {
      DIST8P(jq)
      int j0 = jbase + jq * 8 + half4;
      RIPX8(tv, ti, d0, j0 + 0); RIPX8(tv, ti, d1, j0 + 1);
      RIPX8(tv, ti, d2, j0 + 2); RIPX8(tv, ti, d3, j0 + 3);
    }
  }

  // merge partner lane's list (snapshot first: partner's mutates during merge).
  float ov[TIDX];
  int oi[TIDX];
#pragma unroll
  for (int s = 0; s < TIDX; ++s) ov[s] = __shfl_xor(tv[s], 1);
#pragma unroll
  for (int s = 0; s < TIDX; ++s) oi[s] = __shfl_xor(ti[s], 1);
#pragma unroll
  for (int s = 0; s < TIDX; ++s) { RIPX8(tv, ti, ov[s], oi[s]); }

  if (!half) {
    // plane-major store: 32 consecutive-qi lanes -> 128B segments per plane.
    float* pl = candvx + (size_t)split * NQ2 + (size_t)(b * NN + i);
#pragma unroll
    for (int s = 0; s < TIDX; ++s) pl[(size_t)s * PLANE] = tv[s];
#pragma unroll
    for (int s = 0; s < TIDX; ++s) pl[(size_t)(s + TIDX) * PLANE] = __int_as_float(ti[s]);
  }
}

// ---------------- final (fused thresh+classify), coalesced reads ----------------
// thr = 20th largest of the 64 tracked values (always <= thr_true).
// No-fire (all splits' 8th value < thr): selection from tracked is exact.
// Fire: store query in fbl; k_fb re-collects with thr as a lower bound.
__global__ void k_final(const float* __restrict__ candvx, int* __restrict__ idxk,
                        float* __restrict__ thrv, int* __restrict__ fbl,
                        int* __restrict__ fbcnt) {
  int qi = blockIdx.x * 64 + threadIdx.x;
  const float* pv = candvx + qi;
#define CV(s, sp) pv[((size_t)(s) * NSPLIT + (sp)) * NQ2]
#define CI(s, sp) __float_as_int(pv[((size_t)((s) + TIDX) * NSPLIT + (sp)) * NQ2])
  float tv[KK];
#pragma unroll
  for (int s = 0; s < KK; ++s) tv[s] = NEGINF;
  float v7max = NEGINF;
#pragma unroll 1
  for (int sp = 0; sp < NSPLIT; ++sp) {
#pragma unroll
    for (int s = 0; s < TIDX; ++s) { RIP(tv, CV(s, sp)); }
    v7max = fmaxf(v7max, CV(TIDX - 1, sp));
  }
  float thr = tv[19];
  thrv[qi] = thr;
  int* op = idxk + (size_t)qi * KK;
  int m = 0;
  bool fb = (v7max >= thr);
  if (!fb) {
#pragma unroll 1
    for (int sp = 0; sp < NSPLIT; ++sp) {
#pragma unroll
      for (int s = 0; s < TIDX; ++s) {
        float v = CV(s, sp);
        if (v > thr) {
          if (m < KK) op[m] = CI(s, sp);
          ++m;
        }
      }
    }
    if (m >= KK) fb = true;  // paranoia: no-fire implies m <= 19
  }
  if (fb) {
    int p = atomicAdd(fbcnt, 1);
    fbl[p] = qi;
    return;
  }
  // fill (KK-m) smallest-j ties at v == thr (all such are tracked when no-fire)
  int need = KK - m;
  int last = -1;
#pragma unroll 1
  for (int r2 = 0; r2 < need; ++r2) {
    int best = 0x7fffffff;
#pragma unroll 1
    for (int sp = 0; sp < NSPLIT; ++sp) {
#pragma unroll
      for (int s = 0; s < TIDX; ++s) {
        if (CV(s, sp) == thr) {
          int jx = CI(s, sp);
          if (jx > last && jx < best) best = jx;
        }
      }
    }
    op[m + r2] = best;
    last = best;
  }
#undef CV
#undef CI
}

// ---------------- fallback: single-pass collect + exact lexicographic select ----
// thr (from k_final) is a LOWER bound on the true 20th value -> {d >= thr}
// is a superset of the top-20 (E[n] ~ 22). One distance pass (chain matches
// DIST8P bit-exactly), then t0 selects top-20 by (d desc, j asc).
__global__ __launch_bounds__(256) void k_fb(const float* __restrict__ x,
                                            const float* __restrict__ hg,
                                            const float* __restrict__ thrv,
                                            const int* __restrict__ fbl,
                                            const int* __restrict__ fbcnt,
                                            int* __restrict__ idxk) {
  __shared__ float xiA[HC];
  __shared__ float xiB[HC];
  __shared__ float db[FBCAP * 2];
  __shared__ int cnt;
  int t = threadIdx.x;
  int nfb = *fbcnt;
  if (nfb > BB * NN) nfb = BB * NN;
#pragma unroll 1
  for (int q = blockIdx.x; q < nfb; q += gridDim.x) {
    int qi = fbl[q];
    int b = qi >> 12;
    int i = qi & (NN - 1);
    const float* xb = x + ((size_t)b * CC + KSKIP) * NN;
    if (t < HC) xiA[t] = xb[t * NN + i];
    else if (t < 2 * HC) xiB[t - HC] = xb[(size_t)t * NN + i];
    if (t == 0) cnt = 0;
    __syncthreads();
    float thr = thrv[qi];
#pragma unroll 1
    for (int j = t; j < NN; j += 256) {
      float s1 = 0.f, s2 = 0.f;
#pragma unroll
      for (int cc = 0; cc < HC; ++cc) s1 = fmaf(xiA[cc], xb[cc * NN + j], s1);
#pragma unroll
      for (int cc = 0; cc < HC; ++cc) s2 = fmaf(xiB[cc], xb[(HC + cc) * NN + j], s2);
      float d = (s1 + s2) - hg[b * NN + j];
      if (d >= thr) {
        int p = atomicAdd(&cnt, 1);
        if (p < FBCAP) { db[p * 2] = d; db[p * 2 + 1] = __int_as_float(j); }
      }
    }
    __syncthreads();
    if (t == 0) {
      int n = cnt;
      if (n > FBCAP) n = FBCAP;
      int* op = idxk + (size_t)qi * KK;
      // exact top-20 by (d desc, j asc): repeated max-scan, consume by -inf
      for (int r = 0; r < KK; ++r) {
        float bd = NEGINF;
        int bj = 0x7fffffff;
        int be = -1;
        for (int e = 0; e < n; ++e) {
          float d = db[e * 2];
          int jx = __float_as_int(db[e * 2 + 1]);
          if (d > bd || (d == bd && jx < bj)) { bd = d; bj = jx; be = e; }
        }
        op[r] = bj;
        if (be >= 0) db[be * 2] = NEGINF;
      }
    }
    __syncthreads();
  }
}

// ---------------- K2: u = W1^T x, v = (W2-W1)^T x, stored (b, n, o) ----------------
__global__ void k_uv(const float* __restrict__ x, const float* __restrict__ W,
                     float* __restrict__ ut, float* __restrict__ vt) {
  __shared__ float w1[64 * 65];
  __shared__ float wd[64 * 65];
  __shared__ float xs[64 * 72];
  int t = threadIdx.x;
  int b = blockIdx.x >> 6;
  int nbase = (blockIdx.x & 63) * 64;

  for (int f = t; f < 4096; f += 256) {
    int o = f >> 6, c = f & 63;
    float a = W[o * 128 + c];
    float b2 = W[o * 128 + 64 + c];
    w1[c * 65 + o] = a;
    wd[c * 65 + o] = b2 - a;
  }
  for (int f = t; f < 1024; f += 256) {
    int c = f >> 4, q = f & 15;
    float4 v = *(const float4*)(x + ((size_t)b * CC + c) * NN + nbase + q * 4);
    *(float4*)(xs + c * 72 + q * 4) = v;
  }
  __syncthreads();

  int o = t & 63, w = t >> 6;
  float4 au[4], av[4];
#pragma unroll
  for (int nq = 0; nq < 4; ++nq) {
    au[nq] = make_float4(0.f, 0.f, 0.f, 0.f);
    av[nq] = make_float4(0.f, 0.f, 0.f, 0.f);
  }
#pragma unroll 4
  for (int c = 0; c < 64; ++c) {
    float w1v = w1[c * 65 + o];
    float wdv = wd[c * 65 + o];
#pragma unroll
    for (int nq = 0; nq < 4; ++nq) {
      float4 xv = *(const float4*)(xs + c * 72 + w * 16 + nq * 4);
      au[nq].x = fmaf(w1v, xv.x, au[nq].x);
      au[nq].y = fmaf(w1v, xv.y, au[nq].y);
      au[nq].z = fmaf(w1v, xv.z, au[nq].z);
      au[nq].w = fmaf(w1v, xv.w, au[nq].w);
      av[nq].x = fmaf(wdv, xv.x, av[nq].x);
      av[nq].y = fmaf(wdv, xv.y, av[nq].y);
      av[nq].z = fmaf(wdv, xv.z, av[nq].z);
      av[nq].w = fmaf(wdv, xv.w, av[nq].w);
    }
  }
#pragma unroll
  for (int nq = 0; nq < 4; ++nq) {
    int n = nbase + w * 16 + nq * 4;
    size_t base = ((size_t)b * NN + n) * OO + o;
    ut[base + 0 * OO] = au[nq].x;
    ut[base + 1 * OO] = au[nq].y;
    ut[base + 2 * OO] = au[nq].z;
    ut[base + 3 * OO] = au[nq].w;
    vt[base + 0 * OO] = av[nq].x;
    vt[base + 1 * OO] = av[nq].y;
    vt[base + 2 * OO] = av[nq].z;
    vt[base + 3 * OO] = av[nq].w;
  }
}

// ---------------- K3: BN sum/sumsq + per-(n,o) max of (u+v) ----------------
__global__ void k_stats(const float* __restrict__ ut, const float* __restrict__ vt,
                        const int* __restrict__ idxk, float* __restrict__ gsum,
                        float* __restrict__ gsqs, float* __restrict__ mxv) {
  __shared__ float red[2][4][64];
  int t = threadIdx.x;
  int o = t & 63, w = t >> 6;
  int b = blockIdx.x >> 6;
  int nbase = (blockIdx.x & 63) * 64 + w * 16;
  const float* up = ut + (size_t)b * NN * OO;
  float s = 0.f, s2 = 0.f;
#pragma unroll 1
  for (int nn2 = 0; nn2 < 16; ++nn2) {
    int n = nbase + nn2;
    float vv = vt[((size_t)b * NN + n) * OO + o];
    const int* ip = idxk + ((size_t)b * NN + n) * KK;
    int4 q0 = *(const int4*)(ip + 0);
    int4 q1 = *(const int4*)(ip + 4);
    int4 q2 = *(const int4*)(ip + 8);
    int4 q3 = *(const int4*)(ip + 12);
    int4 q4 = *(const int4*)(ip + 16);
    float mx = NEGINF;
#define ACC(j)                                  \
    {                                           \
      float u = up[(size_t)(j) * OO + o];       \
      float yy = u + vv;                        \
      s += yy;                                  \
      s2 = fmaf(yy, yy, s2);                    \
      mx = fmaxf(mx, yy);                       \
    }
    ACC(q0.x) ACC(q0.y) ACC(q0.z) ACC(q0.w)
    ACC(q1.x) ACC(q1.y) ACC(q1.z) ACC(q1.w)
    ACC(q2.x) ACC(q2.y) ACC(q2.z) ACC(q2.w)
    ACC(q3.x) ACC(q3.y) ACC(q3.z) ACC(q3.w)
    ACC(q4.x) ACC(q4.y) ACC(q4.z) ACC(q4.w)
#undef ACC
    mxv[((size_t)b * NN + n) * OO + o] = mx;
  }
  red[0][w][o] = s;
  red[1][w][o] = s2;
  __syncthreads();
  if (w == 0) {
    float ts = red[0][0][o] + red[0][1][o] + red[0][2][o] + red[0][3][o];
    float t2 = red[1][0][o] + red[1][1][o] + red[1][2][o] + red[1][3][o];
    atomicAdd(&gsum[o], ts);
    atomicAdd(&gsqs[o], t2);
  }
}

// ---------------- K4: finalize BN affine ----------------
__global__ void k_bn(const float* __restrict__ gsum, const float* __restrict__ gsqs,
                     const float* __restrict__ gamma, const float* __restrict__ beta,
                     float* __restrict__ AB) {
  int o = threadIdx.x;
  float mean = gsum[o] * (1.f / M_TOTAL);
  float var = gsqs[o] * (1.f / M_TOTAL) - mean * mean;
  float A = gamma[o] / sqrtf(var + BN_EPS);
  AB[o] = A;
  AB[64 + o] = beta[o] - mean * A;
}

// ---------------- K5: y = leakyrelu(A*mx+B) elementwise + transposed store ----
// A >= 0 (always in practice): max_k lrelu(A*yy_k+B) == lrelu(A*mx+B)
// bit-exactly (fmaf/lrelu monotone, fp rounding monotone). A < 0: exec-masked
// exact gather fallback (P ~ 0: gamma ~ N(1, 0.1)).
__global__ void k_out(const float* __restrict__ ut, const float* __restrict__ vt,
                      const int* __restrict__ idxk, const float* __restrict__ mxv,
                      const float* __restrict__ AB, float* __restrict__ outp) {
  __shared__ float lt[64 * 65];
  int t = threadIdx.x;
  int o = t & 63, w = t >> 6;
  int b = blockIdx.x >> 6;
  int nb = (blockIdx.x & 63) * 64;
  float A = AB[o], Bs = AB[64 + o];
  const float* up = ut + (size_t)b * NN * OO;
#pragma unroll 1
  for (int nn2 = 0; nn2 < 16; ++nn2) {
    int nl = w * 16 + nn2;
    int n = nb + nl;
    float y;
    if (A >= 0.f) {
      float mx = mxv[((size_t)b * NN + n) * OO + o];
      float z = fmaf(A, mx, Bs);
      y = fmaxf(z, NEG * z);
    } else {
      float vv = vt[((size_t)b * NN + n) * OO + o];
      const int* ip = idxk + ((size_t)b * NN + n) * KK;
      float m = NEGINF;
#pragma unroll 1
      for (int e = 0; e < KK; ++e) {
        float u = up[(size_t)ip[e] * OO + o];
        float z = fmaf(A, u + vv, Bs);
        z = fmaxf(z, NEG * z);
        m = fmaxf(m, z);
      }
      y = m;
    }
    lt[nl * 65 + o] = y;
  }
  __syncthreads();
  int oo = t >> 2, part = t & 3;
#pragma unroll
  for (int mq = 0; mq < 4; ++mq) {
    int n0 = part * 16 + mq * 4;
    float4 vvv;
    vvv.x = lt[(n0 + 0) * 65 + oo];
    vvv.y = lt[(n0 + 1) * 65 + oo];
    vvv.z = lt[(n0 + 2) * 65 + oo];
    vvv.w = lt[(n0 + 3) * 65 + oo];
    *(float4*)(outp + ((size_t)b * OO + oo) * NN + nb + n0) = vvv;
  }
}

extern "C" void kernel_launch(void* const* d_in, const int* in_sizes, int n_in,
                              void* d_out, int out_size, void* d_ws, size_t ws_size,
                              hipStream_t stream) {
  const float* x = (const float*)d_in[0];
  const float* W = (const float*)d_in[1];
  const float* gamma = (const float*)d_in[2];
  const float* beta = (const float*)d_in[3];
  float* outp = (float*)d_out;
  char* ws = (char*)d_ws;

  const size_t NQ = (size_t)BB * NN;  // 32768 queries
  size_t off = 0;
  float* hg = (float*)(ws + off); off += NQ * 4;                      // 128 KB
  float* thrv = (float*)(ws + off); off += NQ * 4;                    // 128 KB
  int* idxk = (int*)(ws + off); off += NQ * KK * 4;                   // 2.6 MB
  int* fbcnt = (int*)(ws + off); off += 256;
  int* fbl = (int*)(ws + off); off += NQ * 4;                         // 128 KB
  float* gsum = (float*)(ws + off); off += 256;
  float* gsqs = (float*)(ws + off); off += 256;
  float* AB = (float*)(ws + off); off += 512;
  // overlapped region:
  //  phase 1 (knnA/final/fb): candvx = 16 planes x 1 MB = 16.8 MB
  //  phase 2 (uv/stats/out): ut (8MB) + vt (8MB) + mxv (8MB) = 24 MB
  char* region = ws + off;
  float* candvx = (float*)region;                                     // 16.8 MB
  float* ut = (float*)region;                                         // 8 MB
  float* vt = (float*)(region + NQ * OO * 4);                         // 8 MB
  float* mxv = (float*)(region + 2 * NQ * OO * 4);                    // 8 MB

  k_sq<<<BB * NN / 64, 64, 0, stream>>>(x, hg);
  k_knnA<<<BB * 32 * NSPLIT, 256, 0, stream>>>(x, hg, candvx);
  hipMemsetAsync(fbcnt, 0, 4, stream);
  k_final<<<BB * NN / 64, 64, 0, stream>>>(candvx, idxk, thrv, fbl, fbcnt);
  k_fb<<<256, 256, 0, stream>>>(x, hg, thrv, fbl, fbcnt, idxk);
  k_uv<<<BB * 64, 256, 0, stream>>>(x, W, ut, vt);
  hipMemsetAsync(gsum, 0, 512, stream);
  k_stats<<<BB * 64, 256, 0, stream>>>(ut, vt, idxk, gsum, gsqs, mxv);
  k_bn<<<1, 64, 0, stream>>>(gsum, gsqs, gamma, beta, AB);
  k_out<<<BB * 64, 256, 0, stream>>>(ut, vt, idxk, mxv, AB, outp);
}